// Round 16
// baseline (225.721 us; speedup 1.0000x reference)
//
#include <hip/hip_runtime.h>
#include <hip/hip_bf16.h>
#include <math.h>

typedef __attribute__((ext_vector_type(8))) short bf16x8;
typedef __attribute__((ext_vector_type(4))) float f32x4;

typedef const __attribute__((address_space(1))) unsigned int guint;
typedef __attribute__((address_space(3))) unsigned int luint;

static __device__ __forceinline__ short f2bf(float f) {
    union { float f; unsigned u; } a; a.f = f;
    unsigned r = 0x7FFFu + ((a.u >> 16) & 1u);
    return (short)((a.u + r) >> 16);
}
static __device__ __forceinline__ float bf2f(short s) {
    union { unsigned u; float f; } a;
    a.u = ((unsigned)(unsigned short)s) << 16;
    return a.f;
}

// ---------------------------------------------------------------------------
// Weight prep, ONE launch, grid (16,16,4):
//   z=0: WqT*qscale -> slot0   z=1: WkT -> slot1   (slots 0-1 = WqkT, 1024x512)
//   z=2: WpT -> slot2          z=3: cast Wv (c,d) -> slot3
// ---------------------------------------------------------------------------
__global__ __launch_bounds__(256)
void prep_w(const float* __restrict__ Wq, const float* __restrict__ Wk,
            const float* __restrict__ Wp, const float* __restrict__ Wv,
            short* __restrict__ wT, float qscale)
{
    const int z = blockIdx.z;
    const int tx = threadIdx.x & 31, ty = threadIdx.x >> 5;
    const int c0 = blockIdx.y * 32, d0 = blockIdx.x * 32;
    short* O = wT + (long long)z * 262144;
    if (z == 3) {  // cast Wv, layout preserved (c,d)
#pragma unroll
        for (int r = 0; r < 4; ++r) {
            const int idx = (c0 + ty + 8 * r) * 512 + d0 + tx;
            O[idx] = f2bf(Wv[idx]);
        }
        return;
    }
    __shared__ float ld[32][33];
    const float* W = (z == 0) ? Wq : (z == 1) ? Wk : Wp;
    const float sc = (z == 0) ? qscale : 1.f;
#pragma unroll
    for (int r = 0; r < 4; ++r)
        ld[ty + 8 * r][tx] = W[(long long)(c0 + ty + 8 * r) * 512 + d0 + tx];
    __syncthreads();
#pragma unroll
    for (int r = 0; r < 4; ++r)
        O[(long long)(d0 + ty + 8 * r) * 512 + c0 + tx] = f2bf(ld[tx][ty + 8 * r] * sc);
}

__global__ __launch_bounds__(256)
void concat_bias(const float* __restrict__ bq, const float* __restrict__ bk,
                 float* __restrict__ bqk, float qscale)
{
    int i = blockIdx.x * 256 + threadIdx.x;  // grid 4
    bqk[i] = (i < 512) ? bq[i] * qscale : bk[i - 512];
}

// ---------------------------------------------------------------------------
// b2[o] = sum_d bv[d] Wp[d][o] + bp[o]   (grid 16, 8-way K-split + reduce)
// ---------------------------------------------------------------------------
__global__ __launch_bounds__(256)
void b2_pre(const float* __restrict__ Wp, const float* __restrict__ bp,
            const float* __restrict__ bv, float* __restrict__ b2)
{
    __shared__ float red[256];
    const int t = threadIdx.x;
    const int o = blockIdx.x * 32 + (t >> 3);
    const int part = t & 7;
    float a = 0.f;
    for (int d = part * 64; d < part * 64 + 64; ++d)
        a += bv[d] * Wp[d * 512 + o];
    red[t] = a; __syncthreads();
    if (part < 4) red[t] += red[t + 4];
    __syncthreads();
    if (part < 2) red[t] += red[t + 2];
    __syncthreads();
    if (part == 0) b2[o] = red[t] + red[t + 1] + bp[o];
}

// ---------------------------------------------------------------------------
// Small NT GEMM for the 512^3 Avp precompute: 128^2 tile, 4 waves, grid 16.
// ---------------------------------------------------------------------------
__global__ __launch_bounds__(256)
void small_nt(const short* __restrict__ A, const short* __restrict__ B,
              short* __restrict__ C, float scale, int K,
              int lda, int ldb, int ldc, int tilesM)
{
    __shared__ short lsA[128 * 64];
    __shared__ short lsB[128 * 64];
    const int m0 = (blockIdx.x % tilesM) * 128;
    const int n0 = (blockIdx.x / tilesM) * 128;
    const int t = threadIdx.x;
    const int lane = t & 63;
    const int w = t >> 6;
    const int wr = w >> 1, wc = w & 1;
    const int lr16 = lane & 15, lkg = lane >> 4;
    const int srow = 32 * w + (lane >> 3);
    const int scol = (lane & 7) * 8;
    const short* gA = A + (long long)(m0 + srow) * lda + scol;
    const short* gB = B + (long long)(n0 + srow) * ldb + scol;

    f32x4 acc[4][4];
#pragma unroll
    for (int i = 0; i < 4; ++i)
#pragma unroll
        for (int j = 0; j < 4; ++j) acc[i][j] = (f32x4){0.f, 0.f, 0.f, 0.f};

    const int nk = K >> 6;
    for (int kt = 0; kt < nk; ++kt) {
        const short* ga = gA + kt * 64;
        const short* gb = gB + kt * 64;
#pragma unroll
        for (int c = 0; c < 4; ++c) {
            __builtin_amdgcn_global_load_lds(
                (guint*)(ga + (long long)(8 * c) * lda),
                (luint*)&lsA[(32 * w + 8 * c) * 64], 16, 0, 0);
            __builtin_amdgcn_global_load_lds(
                (guint*)(gb + (long long)(8 * c) * ldb),
                (luint*)&lsB[(32 * w + 8 * c) * 64], 16, 0, 0);
        }
        __syncthreads();
#pragma unroll
        for (int ks = 0; ks < 2; ++ks) {
            bf16x8 af[4], bfr[4];
#pragma unroll
            for (int mi = 0; mi < 4; ++mi)
                af[mi] = *reinterpret_cast<const bf16x8*>(
                    &lsA[(wr * 64 + mi * 16 + lr16) * 64 + ks * 32 + lkg * 8]);
#pragma unroll
            for (int ni = 0; ni < 4; ++ni)
                bfr[ni] = *reinterpret_cast<const bf16x8*>(
                    &lsB[(wc * 64 + ni * 16 + lr16) * 64 + ks * 32 + lkg * 8]);
#pragma unroll
            for (int mi = 0; mi < 4; ++mi)
#pragma unroll
                for (int ni = 0; ni < 4; ++ni)
                    acc[mi][ni] = __builtin_amdgcn_mfma_f32_16x16x32_bf16(
                        af[mi], bfr[ni], acc[mi][ni], 0, 0, 0);
        }
        __syncthreads();
    }
#pragma unroll
    for (int mi = 0; mi < 4; ++mi)
#pragma unroll
        for (int ni = 0; ni < 4; ++ni) {
            const int col = n0 + wc * 64 + ni * 16 + lr16;
#pragma unroll
            for (int j = 0; j < 4; ++j) {
                const int rrow = m0 + wr * 64 + mi * 16 + lkg * 4 + j;
                C[(long long)rrow * ldc + col] = f2bf(acc[mi][ni][j] * scale);
            }
        }
}

// ---------------------------------------------------------------------------
// FUSED GroupNorm: one block per (b,g); 16 ch x 1024 spatial LDS-resident.
// Writes hn blocked [b][g][s][16c] AND hnT (b,c,t).
// ---------------------------------------------------------------------------
__global__ __launch_bounds__(256)
void gn_fused(const float* __restrict__ x, const float* __restrict__ gamma,
              const float* __restrict__ beta, short* __restrict__ hn,
              short* __restrict__ hnT)
{
    __shared__ float xs[16 * 1024];    // 64 KB
    __shared__ float red[256];
    const int bg = blockIdx.x;         // b*32+g
    const int g  = bg & 31, b = bg >> 5;
    const int t  = threadIdx.x;
    const float4* px = reinterpret_cast<const float4*>(x + (long long)bg * 16384);
    float s = 0.f, ss = 0.f;
#pragma unroll
    for (int i = 0; i < 16; ++i) {
        float4 v = px[t + 256 * i];
        reinterpret_cast<float4*>(xs)[t + 256 * i] = v;
        s  += v.x + v.y + v.z + v.w;
        ss += v.x * v.x + v.y * v.y + v.z * v.z + v.w * v.w;
    }
    red[t] = s; __syncthreads();
    for (int o = 128; o > 0; o >>= 1) {
        if (t < o) red[t] += red[t + o];
        __syncthreads();
    }
    const float mean = red[0] * (1.f / 16384.f);
    __syncthreads();
    red[t] = ss; __syncthreads();
    for (int o = 128; o > 0; o >>= 1) {
        if (t < o) red[t] += red[t + o];
        __syncthreads();
    }
    const float var  = red[0] * (1.f / 16384.f) - mean * mean;
    const float rstd = rsqrtf(var + 1e-6f);

    const int half = t & 1;
    float ga[8], be[8];
#pragma unroll
    for (int cc = 0; cc < 8; ++cc) {
        ga[cc] = gamma[g * 16 + half * 8 + cc];
        be[cc] = beta[g * 16 + half * 8 + cc];
    }
    short* outB = hn + (long long)bg * 16384;
#pragma unroll
    for (int it = 0; it < 8; ++it) {
        const int sidx = it * 128 + (t >> 1);
        bf16x8 o;
#pragma unroll
        for (int cc = 0; cc < 8; ++cc) {
            float v = xs[(half * 8 + cc) * 1024 + sidx];
            o[cc] = f2bf((v - mean) * rstd * ga[cc] + be[cc]);
        }
        *reinterpret_cast<bf16x8*>(outB + sidx * 16 + half * 8) = o;
    }
    short* oT = hnT + ((long long)b * 512 + g * 16) * 1024;
#pragma unroll
    for (int cc = 0; cc < 16; ++cc) {
        const float g_ = gamma[g * 16 + cc], b_ = beta[g * 16 + cc];
        const int pos = t * 4;
        short4 o4;
        o4.x = f2bf((xs[cc * 1024 + pos + 0] - mean) * rstd * g_ + b_);
        o4.y = f2bf((xs[cc * 1024 + pos + 1] - mean) * rstd * g_ + b_);
        o4.z = f2bf((xs[cc * 1024 + pos + 2] - mean) * rstd * g_ + b_);
        o4.w = f2bf((xs[cc * 1024 + pos + 3] - mean) * rstd * g_ + b_);
        *reinterpret_cast<short4*>(oT + cc * 1024 + pos) = o4;
    }
}

// ---------------------------------------------------------------------------
// NT GEMM, 256x256 / 8-wave / two-phase-per-K-tile — R10/R15 de-fenced
// schedule + T5 setprio around the MFMA clusters (m218b: +21-39% when waves
// have role diversity; R10 removed it bundled with the fences — untested
// unbundled until now). Everything else identical to R15.
// ---------------------------------------------------------------------------
template<int BIAS_M, int BIAS_N, int RESID, int EXPRS, int DIVROW4, int HN_A, int HN_B>
__global__ __launch_bounds__(512, 1)
void nt_gemm(const short* __restrict__ A, const short* __restrict__ B,
             void* __restrict__ Cv,
             const float* __restrict__ biasM, const float* __restrict__ biasN,
             const float* __restrict__ resid, float* __restrict__ rs,
             float scale, int K, int lda, int ldb, int ldc,
             long long sA, long long sB, long long sC,
             int tilesM, int tilesPerBatch)
{
    __shared__ short lsA[2][2][128 * 64];   // [buf][Mhalf] 16 KB regions
    __shared__ short lsB[2][2][128 * 64];   // 128 KB total

    const int id = blockIdx.x;
    const int chunk = gridDim.x >> 3;
    const int gid = chunk ? ((id & 7) * chunk + (id >> 3)) : id;
    const int bz = gid / tilesPerBatch;
    const int tt = gid - bz * tilesPerBatch;
    const int m0 = (tt % tilesM) * 256;
    const int n0 = (tt / tilesM) * 256;

    const int t = threadIdx.x;           // 0..511
    const int lane = t & 63;
    const int w = t >> 6;                // 0..7
    const int wrs = w >> 1;              // row strip 0..3 (32 rows/quadrant)
    const int wcs = w & 1;               // col strip 0..1 (64 cols/quadrant)
    const int lr16 = lane & 15, lkg = lane >> 4;
    const int sw = lr16 & 7;             // read-side swizzle key (row & 7)

    const int srow = t >> 3;             // 0..63
    const int jch  = (t & 7) ^ (srow & 7);         // pre-swizzled chunk 0..7
    const int scol = jch * 8;

    const short* gA; int rsA, ktA;
    if (HN_A) {
        gA = A + ((long long)bz * 32 + (jch >> 1)) * 16384
               + (long long)(m0 + srow) * 16 + (jch & 1) * 8;
        rsA = 16; ktA = 65536;
    } else {
        gA = A + (long long)bz * sA + (long long)(m0 + srow) * lda + scol;
        rsA = lda; ktA = 64;
    }
    const short* gB; int rsB, ktB;
    if (HN_B) {
        gB = B + ((long long)bz * 32 + (jch >> 1)) * 16384
               + (long long)(n0 + srow) * 16 + (jch & 1) * 8;
        rsB = 16; ktB = 65536;
    } else {
        gB = B + (long long)bz * sB + (long long)(n0 + srow) * ldb + scol;
        rsB = ldb; ktB = 64;
    }

    f32x4 acc[4][2][4];                  // [quadrant ah*2+bh][mi2][ni]
#pragma unroll
    for (int q = 0; q < 4; ++q)
#pragma unroll
        for (int i = 0; i < 2; ++i)
#pragma unroll
            for (int j = 0; j < 4; ++j) acc[q][i][j] = (f32x4){0.f, 0.f, 0.f, 0.f};

    const int nk = K >> 6;               // even (8 or 16)

#define STAGE_A(buf, h, kt)                                                    \
    {                                                                          \
        _Pragma("unroll")                                                      \
        for (int c = 0; c < 2; ++c)                                            \
            __builtin_amdgcn_global_load_lds(                                  \
                (guint*)(gA + (long long)(kt) * ktA                            \
                            + (long long)((h) * 128 + 64 * c) * rsA),          \
                (luint*)&lsA[buf][h][t * 8 + 4096 * c], 16, 0, 0);             \
    }
#define STAGE_B(buf, h, kt)                                                    \
    {                                                                          \
        _Pragma("unroll")                                                      \
        for (int c = 0; c < 2; ++c)                                            \
            __builtin_amdgcn_global_load_lds(                                  \
                (guint*)(gB + (long long)(kt) * ktB                            \
                            + (long long)((h) * 128 + 64 * c) * rsB),          \
                (luint*)&lsB[buf][h][t * 8 + 4096 * c], 16, 0, 0);             \
    }

#define LDA_HALF(dst, buf, h)                                                  \
    _Pragma("unroll")                                                          \
    for (int mi2 = 0; mi2 < 2; ++mi2)                                          \
        _Pragma("unroll")                                                      \
        for (int ks = 0; ks < 2; ++ks)                                         \
            dst[mi2][ks] = *reinterpret_cast<const bf16x8*>(                   \
                &lsA[buf][h][(wrs * 32 + mi2 * 16 + lr16) * 64 +               \
                             (((ks * 4 + lkg) ^ sw) * 8)]);
#define LDB_HALF(dst, buf, h)                                                  \
    _Pragma("unroll")                                                          \
    for (int ni = 0; ni < 4; ++ni)                                             \
        _Pragma("unroll")                                                      \
        for (int ks = 0; ks < 2; ++ks)                                         \
            dst[ni][ks] = *reinterpret_cast<const bf16x8*>(                    \
                &lsB[buf][h][(wcs * 64 + ni * 16 + lr16) * 64 +                \
                             (((ks * 4 + lkg) ^ sw) * 8)]);

#define MFMAQ(q, Af, Bf)                                                       \
    _Pragma("unroll")                                                          \
    for (int ks = 0; ks < 2; ++ks)                                             \
        _Pragma("unroll")                                                      \
        for (int mi2 = 0; mi2 < 2; ++mi2)                                      \
            _Pragma("unroll")                                                  \
            for (int ni = 0; ni < 4; ++ni)                                     \
                acc[q][mi2][ni] = __builtin_amdgcn_mfma_f32_16x16x32_bf16(     \
                    Af[mi2][ks], Bf[ni][ks], acc[q][mi2][ni], 0, 0, 0);

#define PH_END(N)                                                              \
    asm volatile("s_waitcnt vmcnt(" #N ")" ::: "memory");                      \
    __builtin_amdgcn_s_barrier();                                              \
    __builtin_amdgcn_sched_barrier(0)

#define FRAME(b, kt)                                                           \
    {                                                                          \
        bf16x8 a0[2][2], a1[2][2], b0f[4][2], b1f[4][2];                       \
        /* ---- phase A: quadrants (0,0), (0,1) ---- */                        \
        LDB_HALF(b0f, b, 0)                                                    \
        LDA_HALF(a0, b, 0)                                                     \
        LDB_HALF(b1f, b, 1)                                                    \
        STAGE_B((b) ^ 1, 0, (kt) + 1);                                         \
        STAGE_B((b) ^ 1, 1, (kt) + 1);                                         \
        STAGE_A((b) ^ 1, 0, (kt) + 1);                                         \
        __builtin_amdgcn_s_setprio(1);                                         \
        MFMAQ(0, a0, b0f)                                                      \
        MFMAQ(1, a0, b1f)                                                      \
        __builtin_amdgcn_s_setprio(0);                                         \
        PH_END(6);                                                             \
        /* ---- phase B: quadrants (1,0), (1,1) — B frags persist ---- */      \
        LDA_HALF(a1, b, 1)                                                     \
        STAGE_A((b) ^ 1, 1, (kt) + 1);                                         \
        __builtin_amdgcn_s_setprio(1);                                         \
        MFMAQ(2, a1, b0f)                                                      \
        MFMAQ(3, a1, b1f)                                                      \
        __builtin_amdgcn_s_setprio(0);                                         \
        PH_END(2);                                                             \
    }

    STAGE_B(0, 0, 0); STAGE_B(0, 1, 0); STAGE_A(0, 0, 0);
    STAGE_A(0, 1, 0);
    PH_END(2);

    for (int kt = 0; kt < nk; kt += 2) {
        FRAME(0, kt)
        FRAME(1, kt + 1)
    }
#undef STAGE_A
#undef STAGE_B
#undef LDA_HALF
#undef LDB_HALF
#undef MFMAQ
#undef PH_END
#undef FRAME

    // epilogue: D layout col=lane&15, row=(lane>>4)*4+reg (m89-verified)
    float psum[2][2][4];
    if (EXPRS) {
#pragma unroll
        for (int ah = 0; ah < 2; ++ah)
#pragma unroll
            for (int mi2 = 0; mi2 < 2; ++mi2)
#pragma unroll
                for (int j = 0; j < 4; ++j) psum[ah][mi2][j] = 0.f;
    }
#pragma unroll
    for (int ah = 0; ah < 2; ++ah) {
#pragma unroll
        for (int bh = 0; bh < 2; ++bh) {
#pragma unroll
            for (int mi2 = 0; mi2 < 2; ++mi2) {
                float addm[4], mul[4];
#pragma unroll
                for (int j = 0; j < 4; ++j) {
                    const int rrow = m0 + ah * 128 + wrs * 32 + mi2 * 16 + lkg * 4 + j;
                    addm[j] = BIAS_M ? biasM[rrow] : 0.f;
                    if (DIVROW4) {
                        const float* r4 = rs + (long long)bz * 4096 + rrow;
                        mul[j] = 1.f / (r4[0] + r4[1024] + r4[2048] + r4[3072]);
                    } else mul[j] = 1.f;
                }
#pragma unroll
                for (int ni = 0; ni < 4; ++ni) {
                    const int col = n0 + bh * 128 + wcs * 64 + ni * 16 + lr16;
                    float bn = BIAS_N ? biasN[col] : 0.f;
#pragma unroll
                    for (int j = 0; j < 4; ++j) {
                        const int rrow = m0 + ah * 128 + wrs * 32 + mi2 * 16 + lkg * 4 + j;
                        float v2 = acc[ah * 2 + bh][mi2][ni][j] + addm[j] + bn;
                        v2 *= scale;
                        if (EXPRS) { v2 = __expf(v2 - 8.f); psum[ah][mi2][j] += v2; }
                        if (DIVROW4) v2 *= mul[j];
                        const long long idx = (long long)rrow * ldc + col;
                        if (RESID) {
                            float* Cf = (float*)Cv + (long long)bz * sC;
                            Cf[idx] = v2 + resid[(long long)bz * sC + idx];
                        } else {
                            short* Cs = (short*)Cv + (long long)bz * sC;
                            Cs[idx] = f2bf(v2);
                        }
                    }
                }
            }
        }
    }
    if (EXPRS) {
#pragma unroll
        for (int ah = 0; ah < 2; ++ah)
#pragma unroll
            for (int mi2 = 0; mi2 < 2; ++mi2)
#pragma unroll
                for (int j = 0; j < 4; ++j) {
                    float v = psum[ah][mi2][j];
                    v += __shfl_xor(v, 1); v += __shfl_xor(v, 2);
                    v += __shfl_xor(v, 4); v += __shfl_xor(v, 8);
                    psum[ah][mi2][j] = v;
                }
        float* scr = (float*)&lsA[1][0][0];
        __syncthreads();
        if (lr16 == 0) {
#pragma unroll
            for (int ah = 0; ah < 2; ++ah)
#pragma unroll
                for (int mi2 = 0; mi2 < 2; ++mi2)
#pragma unroll
                    for (int j = 0; j < 4; ++j)
                        scr[wcs * 256 + ah * 128 + wrs * 32 + mi2 * 16 + lkg * 4 + j]
                            = psum[ah][mi2][j];
        }
        __syncthreads();
        if (t < 256)
            rs[(long long)bz * 4096 + (n0 >> 8) * 1024 + m0 + t]
                = scr[t] + scr[256 + t];
    }
}

// ---------------------------------------------------------------------------
extern "C" void kernel_launch(void* const* d_in, const int* in_sizes, int n_in,
                              void* d_out, int out_size, void* d_ws, size_t ws_size,
                              hipStream_t stream)
{
    (void)in_sizes; (void)n_in; (void)out_size; (void)ws_size;
    const float* x     = (const float*)d_in[0];
    const float* gamma = (const float*)d_in[1];
    const float* beta  = (const float*)d_in[2];
    const float* Wq = (const float*)d_in[3];
    const float* bq = (const float*)d_in[4];
    const float* Wk = (const float*)d_in[5];
    const float* bk = (const float*)d_in[6];
    const float* Wv = (const float*)d_in[7];
    const float* bv = (const float*)d_in[8];
    const float* Wp = (const float*)d_in[9];
    const float* bp = (const float*)d_in[10];
    float* out = (float*)d_out;

    // Workspace (time-overlapped), high-water 162.51 MB — as R15:
    //   [0,32M):    hnT (b,c,t) bf16          (gn -> Phn)
    //   [32,96M):   qkb (b,s,1024) bf16       (qk -> expS); Phn reuses [32,64M)
    //   [96,128M):  hn blocked bf16           (gn -> qk, dead before expS)
    //   [96,160M):  expS (b,s,t) bf16         (expS -> Phn; overlays dead hn)
    //   [160,162M): wT slots {WqT*qs, WkT, WpT, Wv-cast}
    //   [162M..):   Avp (512K) | bqk (4K) | b2 (2K)
    //   rs4 (512K f32) lives in d_out: written by expS, read by Phn, then
    //   fully overwritten by the final out-GEMM (dead by then).
    char* ws = (char*)d_ws;
    short*  hnT  = (short*)ws;
    short*  qkb  = (short*)(ws + (32LL << 20));
    short*  hn   = (short*)(ws + (96LL << 20));
    short*  expS = (short*)(ws + (96LL << 20));   // overlays hn (dead)
    short*  wT   = (short*)(ws + (160LL << 20));
    short*  Avp  = (short*)(ws + (162LL << 20));
    float*  bqk  = (float*)(ws + (162LL << 20) + (512 << 10));
    float*  b2   = bqk + 1024;
    short*  Phn  = qkb;                            // reuses [32,64M)
    float*  rs4  = (float*)d_out;                  // scratch until out-GEMM

    const short* WqkT = wT;                        // slots 0-1 (1024 x 512)
    const short* WpT  = wT + 2 * 262144;
    const short* WvC  = wT + 3 * 262144;

    const float qscale = 0.044194173824159216f;    // 512^-0.5

    // --- precomputes ---
    prep_w<<<dim3(16, 16, 4), 256, 0, stream>>>(Wq, Wk, Wp, Wv, wT, qscale);
    concat_bias<<<dim3(4), 256, 0, stream>>>(bq, bk, bqk, qscale);
    b2_pre<<<dim3(16), 256, 0, stream>>>(Wp, bp, bv, b2);
    // Avp (d'',c) = sum_d WpT[d''][d] * Wv[c][d]  (= (Wv Wp)^T)
    small_nt<<<16, 256, 0, stream>>>(WpT, WvC, Avp, 1.f, 512, 512, 512, 512, 4);

    // --- main pipeline ---
    gn_fused<<<dim3(1024), 256, 0, stream>>>(x, gamma, beta, hn, hnT);

    // qk = hn @ [Wq*qs | Wk] + bqk : M=1024(s), N=1024, K=512 (hn blocked A)
    nt_gemm<0, 1, 0, 0, 0, 1, 0><<<512, 512, 0, stream>>>(
        hn, WqkT, qkb, nullptr, bqk, nullptr, nullptr, 1.f,
        512, 0, 512, 1024, 0, 0, 1024LL * 1024, 4, 16);
    // expS (s,t) = exp(q @ k^T - 8), rs4 partials : M=N=1024, K=512
    nt_gemm<0, 0, 0, 1, 0, 0, 0><<<512, 512, 0, stream>>>(
        qkb, qkb + 512, expS, nullptr, nullptr, nullptr, rs4, 1.f,
        512, 1024, 1024, 1024, 1024LL * 1024, 1024LL * 1024, 1024LL * 1024, 4, 16);
    // Phn (s,c) = (expS @ hnT^T) / rowsum : M=1024, N=512, K=1024
    nt_gemm<0, 0, 0, 0, 1, 0, 0><<<256, 512, 0, stream>>>(
        expS, hnT, Phn, nullptr, nullptr, nullptr, rs4, 1.f,
        1024, 1024, 1024, 512, 1024LL * 1024, 512LL * 1024, 512LL * 1024, 4, 8);
    // out (d'',s) = Avp @ Phn^T + b2 + x : M=512, N=1024, K=512, fp32
    nt_gemm<1, 0, 1, 0, 0, 0, 0><<<256, 512, 0, stream>>>(
        Avp, Phn, out, b2, nullptr, x, nullptr, 1.f,
        512, 512, 512, 1024, 0, 512LL * 1024, 512LL * 1024, 2, 8);
}

// Round 17
// 198.449 us; speedup vs baseline: 1.1374x; 1.1374x over previous
//
#include <hip/hip_runtime.h>
#include <hip/hip_bf16.h>
#include <math.h>

typedef __attribute__((ext_vector_type(8))) short bf16x8;
typedef __attribute__((ext_vector_type(4))) float f32x4;

typedef const __attribute__((address_space(1))) unsigned int guint;
typedef __attribute__((address_space(3))) unsigned int luint;

static __device__ __forceinline__ short f2bf(float f) {
    union { float f; unsigned u; } a; a.f = f;
    unsigned r = 0x7FFFu + ((a.u >> 16) & 1u);
    return (short)((a.u + r) >> 16);
}
static __device__ __forceinline__ float bf2f(short s) {
    union { unsigned u; float f; } a;
    a.u = ((unsigned)(unsigned short)s) << 16;
    return a.f;
}

// ---------------------------------------------------------------------------
// Weight/bias prep, ONE launch, grid (16,16,5):
//   z=0: WqT*qscale -> slot0   z=1: WkT -> slot1  (slots 0-1 = WqkT 1024x512)
//   z=2: WpT -> slot2          z=3: cast Wv (c,d) -> slot3
//   z=4: (y==0,x<16) b2[o] = bv.Wp[:,o] + bp[o];  (y==1,x<4) bqk concat
// ---------------------------------------------------------------------------
__global__ __launch_bounds__(256)
void prep_w(const float* __restrict__ Wq, const float* __restrict__ Wk,
            const float* __restrict__ Wp, const float* __restrict__ Wv,
            const float* __restrict__ bq, const float* __restrict__ bk,
            const float* __restrict__ bp, const float* __restrict__ bv,
            short* __restrict__ wT, float* __restrict__ bqk,
            float* __restrict__ b2, float qscale)
{
    const int z = blockIdx.z;
    const int t = threadIdx.x;
    if (z == 4) {
        if (blockIdx.y == 0 && blockIdx.x < 16) {
            __shared__ float red[256];
            const int o = blockIdx.x * 32 + (t >> 3);
            const int part = t & 7;
            float a = 0.f;
            for (int d = part * 64; d < part * 64 + 64; ++d)
                a += bv[d] * Wp[d * 512 + o];
            red[t] = a; __syncthreads();
            if (part < 4) red[t] += red[t + 4];
            __syncthreads();
            if (part < 2) red[t] += red[t + 2];
            __syncthreads();
            if (part == 0) b2[o] = red[t] + red[t + 1] + bp[o];
        } else if (blockIdx.y == 1 && blockIdx.x < 4) {
            int i = blockIdx.x * 256 + t;
            bqk[i] = (i < 512) ? bq[i] * qscale : bk[i - 512];
        }
        return;
    }
    const int tx = t & 31, ty = t >> 5;
    const int c0 = blockIdx.y * 32, d0 = blockIdx.x * 32;
    short* O = wT + (long long)z * 262144;
    if (z == 3) {  // cast Wv, layout preserved (c,d)
#pragma unroll
        for (int r = 0; r < 4; ++r) {
            const int idx = (c0 + ty + 8 * r) * 512 + d0 + tx;
            O[idx] = f2bf(Wv[idx]);
        }
        return;
    }
    __shared__ float ld[32][33];
    const float* W = (z == 0) ? Wq : (z == 1) ? Wk : Wp;
    const float sc = (z == 0) ? qscale : 1.f;
#pragma unroll
    for (int r = 0; r < 4; ++r)
        ld[ty + 8 * r][tx] = W[(long long)(c0 + ty + 8 * r) * 512 + d0 + tx];
    __syncthreads();
#pragma unroll
    for (int r = 0; r < 4; ++r)
        O[(long long)(d0 + ty + 8 * r) * 512 + c0 + tx] = f2bf(ld[tx][ty + 8 * r] * sc);
}

// ---------------------------------------------------------------------------
// Small NT GEMM for the 512^3 Avp precompute: 128^2 tile, 4 waves, grid 16.
// ---------------------------------------------------------------------------
__global__ __launch_bounds__(256)
void small_nt(const short* __restrict__ A, const short* __restrict__ B,
              short* __restrict__ C, float scale, int K,
              int lda, int ldb, int ldc, int tilesM)
{
    __shared__ short lsA[128 * 64];
    __shared__ short lsB[128 * 64];
    const int m0 = (blockIdx.x % tilesM) * 128;
    const int n0 = (blockIdx.x / tilesM) * 128;
    const int t = threadIdx.x;
    const int lane = t & 63;
    const int w = t >> 6;
    const int wr = w >> 1, wc = w & 1;
    const int lr16 = lane & 15, lkg = lane >> 4;
    const int srow = 32 * w + (lane >> 3);
    const int scol = (lane & 7) * 8;
    const short* gA = A + (long long)(m0 + srow) * lda + scol;
    const short* gB = B + (long long)(n0 + srow) * ldb + scol;

    f32x4 acc[4][4];
#pragma unroll
    for (int i = 0; i < 4; ++i)
#pragma unroll
        for (int j = 0; j < 4; ++j) acc[i][j] = (f32x4){0.f, 0.f, 0.f, 0.f};

    const int nk = K >> 6;
    for (int kt = 0; kt < nk; ++kt) {
        const short* ga = gA + kt * 64;
        const short* gb = gB + kt * 64;
#pragma unroll
        for (int c = 0; c < 4; ++c) {
            __builtin_amdgcn_global_load_lds(
                (guint*)(ga + (long long)(8 * c) * lda),
                (luint*)&lsA[(32 * w + 8 * c) * 64], 16, 0, 0);
            __builtin_amdgcn_global_load_lds(
                (guint*)(gb + (long long)(8 * c) * ldb),
                (luint*)&lsB[(32 * w + 8 * c) * 64], 16, 0, 0);
        }
        __syncthreads();
#pragma unroll
        for (int ks = 0; ks < 2; ++ks) {
            bf16x8 af[4], bfr[4];
#pragma unroll
            for (int mi = 0; mi < 4; ++mi)
                af[mi] = *reinterpret_cast<const bf16x8*>(
                    &lsA[(wr * 64 + mi * 16 + lr16) * 64 + ks * 32 + lkg * 8]);
#pragma unroll
            for (int ni = 0; ni < 4; ++ni)
                bfr[ni] = *reinterpret_cast<const bf16x8*>(
                    &lsB[(wc * 64 + ni * 16 + lr16) * 64 + ks * 32 + lkg * 8]);
#pragma unroll
            for (int mi = 0; mi < 4; ++mi)
#pragma unroll
                for (int ni = 0; ni < 4; ++ni)
                    acc[mi][ni] = __builtin_amdgcn_mfma_f32_16x16x32_bf16(
                        af[mi], bfr[ni], acc[mi][ni], 0, 0, 0);
        }
        __syncthreads();
    }
#pragma unroll
    for (int mi = 0; mi < 4; ++mi)
#pragma unroll
        for (int ni = 0; ni < 4; ++ni) {
            const int col = n0 + wc * 64 + ni * 16 + lr16;
#pragma unroll
            for (int j = 0; j < 4; ++j) {
                const int rrow = m0 + wr * 64 + mi * 16 + lkg * 4 + j;
                C[(long long)rrow * ldc + col] = f2bf(acc[mi][ni][j] * scale);
            }
        }
}

// ---------------------------------------------------------------------------
// FUSED GroupNorm: one block per (b,g); 16 ch x 1024 spatial LDS-resident.
// Writes hn blocked [b][g][s][16c] AND hnT (b,c,t).
// ---------------------------------------------------------------------------
__global__ __launch_bounds__(256)
void gn_fused(const float* __restrict__ x, const float* __restrict__ gamma,
              const float* __restrict__ beta, short* __restrict__ hn,
              short* __restrict__ hnT)
{
    __shared__ float xs[16 * 1024];    // 64 KB
    __shared__ float red[256];
    const int bg = blockIdx.x;         // b*32+g
    const int g  = bg & 31, b = bg >> 5;
    const int t  = threadIdx.x;
    const float4* px = reinterpret_cast<const float4*>(x + (long long)bg * 16384);
    float s = 0.f, ss = 0.f;
#pragma unroll
    for (int i = 0; i < 16; ++i) {
        float4 v = px[t + 256 * i];
        reinterpret_cast<float4*>(xs)[t + 256 * i] = v;
        s  += v.x + v.y + v.z + v.w;
        ss += v.x * v.x + v.y * v.y + v.z * v.z + v.w * v.w;
    }
    red[t] = s; __syncthreads();
    for (int o = 128; o > 0; o >>= 1) {
        if (t < o) red[t] += red[t + o];
        __syncthreads();
    }
    const float mean = red[0] * (1.f / 16384.f);
    __syncthreads();
    red[t] = ss; __syncthreads();
    for (int o = 128; o > 0; o >>= 1) {
        if (t < o) red[t] += red[t + o];
        __syncthreads();
    }
    const float var  = red[0] * (1.f / 16384.f) - mean * mean;
    const float rstd = rsqrtf(var + 1e-6f);

    const int half = t & 1;
    float ga[8], be[8];
#pragma unroll
    for (int cc = 0; cc < 8; ++cc) {
        ga[cc] = gamma[g * 16 + half * 8 + cc];
        be[cc] = beta[g * 16 + half * 8 + cc];
    }
    short* outB = hn + (long long)bg * 16384;
#pragma unroll
    for (int it = 0; it < 8; ++it) {
        const int sidx = it * 128 + (t >> 1);
        bf16x8 o;
#pragma unroll
        for (int cc = 0; cc < 8; ++cc) {
            float v = xs[(half * 8 + cc) * 1024 + sidx];
            o[cc] = f2bf((v - mean) * rstd * ga[cc] + be[cc]);
        }
        *reinterpret_cast<bf16x8*>(outB + sidx * 16 + half * 8) = o;
    }
    short* oT = hnT + ((long long)b * 512 + g * 16) * 1024;
#pragma unroll
    for (int cc = 0; cc < 16; ++cc) {
        const float g_ = gamma[g * 16 + cc], b_ = beta[g * 16 + cc];
        const int pos = t * 4;
        short4 o4;
        o4.x = f2bf((xs[cc * 1024 + pos + 0] - mean) * rstd * g_ + b_);
        o4.y = f2bf((xs[cc * 1024 + pos + 1] - mean) * rstd * g_ + b_);
        o4.z = f2bf((xs[cc * 1024 + pos + 2] - mean) * rstd * g_ + b_);
        o4.w = f2bf((xs[cc * 1024 + pos + 3] - mean) * rstd * g_ + b_);
        *reinterpret_cast<short4*>(oT + cc * 1024 + pos) = o4;
    }
}

// ---------------------------------------------------------------------------
// NT GEMM, 256x256 / 8-wave / two-phase-per-K-tile — R10/R15 de-fenced
// schedule, measured best (R16 confirmed setprio regresses here: lockstep
// at barrier granularity -> m190 regime, reverted). Counted vmcnt only,
// one raw barrier per phase, compiler-scheduled interior.
// HN_A/HN_B: blocked-hn addressing. BIAS_N: global column bias. FIFO vmcnt
// ledger identical to R8/R10 (verified). Both-sides XOR swizzle (0
// conflicts), XCD remap, EXPRS rowsum partials / DIVROW4 divide epilogues.
// ---------------------------------------------------------------------------
template<int BIAS_M, int BIAS_N, int RESID, int EXPRS, int DIVROW4, int HN_A, int HN_B>
__global__ __launch_bounds__(512, 1)
void nt_gemm(const short* __restrict__ A, const short* __restrict__ B,
             void* __restrict__ Cv,
             const float* __restrict__ biasM, const float* __restrict__ biasN,
             const float* __restrict__ resid, float* __restrict__ rs,
             float scale, int K, int lda, int ldb, int ldc,
             long long sA, long long sB, long long sC,
             int tilesM, int tilesPerBatch)
{
    __shared__ short lsA[2][2][128 * 64];   // [buf][Mhalf] 16 KB regions
    __shared__ short lsB[2][2][128 * 64];   // 128 KB total

    const int id = blockIdx.x;
    const int chunk = gridDim.x >> 3;
    const int gid = chunk ? ((id & 7) * chunk + (id >> 3)) : id;
    const int bz = gid / tilesPerBatch;
    const int tt = gid - bz * tilesPerBatch;
    const int m0 = (tt % tilesM) * 256;
    const int n0 = (tt / tilesM) * 256;

    const int t = threadIdx.x;           // 0..511
    const int lane = t & 63;
    const int w = t >> 6;                // 0..7
    const int wrs = w >> 1;              // row strip 0..3 (32 rows/quadrant)
    const int wcs = w & 1;               // col strip 0..1 (64 cols/quadrant)
    const int lr16 = lane & 15, lkg = lane >> 4;
    const int sw = lr16 & 7;             // read-side swizzle key (row & 7)

    const int srow = t >> 3;             // 0..63
    const int jch  = (t & 7) ^ (srow & 7);         // pre-swizzled chunk 0..7
    const int scol = jch * 8;

    const short* gA; int rsA, ktA;
    if (HN_A) {
        gA = A + ((long long)bz * 32 + (jch >> 1)) * 16384
               + (long long)(m0 + srow) * 16 + (jch & 1) * 8;
        rsA = 16; ktA = 65536;
    } else {
        gA = A + (long long)bz * sA + (long long)(m0 + srow) * lda + scol;
        rsA = lda; ktA = 64;
    }
    const short* gB; int rsB, ktB;
    if (HN_B) {
        gB = B + ((long long)bz * 32 + (jch >> 1)) * 16384
               + (long long)(n0 + srow) * 16 + (jch & 1) * 8;
        rsB = 16; ktB = 65536;
    } else {
        gB = B + (long long)bz * sB + (long long)(n0 + srow) * ldb + scol;
        rsB = ldb; ktB = 64;
    }

    f32x4 acc[4][2][4];                  // [quadrant ah*2+bh][mi2][ni]
#pragma unroll
    for (int q = 0; q < 4; ++q)
#pragma unroll
        for (int i = 0; i < 2; ++i)
#pragma unroll
            for (int j = 0; j < 4; ++j) acc[q][i][j] = (f32x4){0.f, 0.f, 0.f, 0.f};

    const int nk = K >> 6;               // even (8 or 16)

#define STAGE_A(buf, h, kt)                                                    \
    {                                                                          \
        _Pragma("unroll")                                                      \
        for (int c = 0; c < 2; ++c)                                            \
            __builtin_amdgcn_global_load_lds(                                  \
                (guint*)(gA + (long long)(kt) * ktA                            \
                            + (long long)((h) * 128 + 64 * c) * rsA),          \
                (luint*)&lsA[buf][h][t * 8 + 4096 * c], 16, 0, 0);             \
    }
#define STAGE_B(buf, h, kt)                                                    \
    {                                                                          \
        _Pragma("unroll")                                                      \
        for (int c = 0; c < 2; ++c)                                            \
            __builtin_amdgcn_global_load_lds(                                  \
                (guint*)(gB + (long long)(kt) * ktB                            \
                            + (long long)((h) * 128 + 64 * c) * rsB),          \
                (luint*)&lsB[buf][h][t * 8 + 4096 * c], 16, 0, 0);             \
    }

#define LDA_HALF(dst, buf, h)                                                  \
    _Pragma("unroll")                                                          \
    for (int mi2 = 0; mi2 < 2; ++mi2)                                          \
        _Pragma("unroll")                                                      \
        for (int ks = 0; ks < 2; ++ks)                                         \
            dst[mi2][ks] = *reinterpret_cast<const bf16x8*>(                   \
                &lsA[buf][h][(wrs * 32 + mi2 * 16 + lr16) * 64 +               \
                             (((ks * 4 + lkg) ^ sw) * 8)]);
#define LDB_HALF(dst, buf, h)                                                  \
    _Pragma("unroll")                                                          \
    for (int ni = 0; ni < 4; ++ni)                                             \
        _Pragma("unroll")                                                      \
        for (int ks = 0; ks < 2; ++ks)                                         \
            dst[ni][ks] = *reinterpret_cast<const bf16x8*>(                    \
                &lsB[buf][h][(wcs * 64 + ni * 16 + lr16) * 64 +                \
                             (((ks * 4 + lkg) ^ sw) * 8)]);

#define MFMAQ(q, Af, Bf)                                                       \
    _Pragma("unroll")                                                          \
    for (int ks = 0; ks < 2; ++ks)                                             \
        _Pragma("unroll")                                                      \
        for (int mi2 = 0; mi2 < 2; ++mi2)                                      \
            _Pragma("unroll")                                                  \
            for (int ni = 0; ni < 4; ++ni)                                     \
                acc[q][mi2][ni] = __builtin_amdgcn_mfma_f32_16x16x32_bf16(     \
                    Af[mi2][ks], Bf[ni][ks], acc[q][mi2][ni], 0, 0, 0);

#define PH_END(N)                                                              \
    asm volatile("s_waitcnt vmcnt(" #N ")" ::: "memory");                      \
    __builtin_amdgcn_s_barrier();                                              \
    __builtin_amdgcn_sched_barrier(0)

#define FRAME(b, kt)                                                           \
    {                                                                          \
        bf16x8 a0[2][2], a1[2][2], b0f[4][2], b1f[4][2];                       \
        /* ---- phase A: quadrants (0,0), (0,1) — no internal fences ---- */   \
        LDB_HALF(b0f, b, 0)                                                    \
        LDA_HALF(a0, b, 0)                                                     \
        LDB_HALF(b1f, b, 1)                                                    \
        STAGE_B((b) ^ 1, 0, (kt) + 1);                                         \
        STAGE_B((b) ^ 1, 1, (kt) + 1);                                         \
        STAGE_A((b) ^ 1, 0, (kt) + 1);                                         \
        MFMAQ(0, a0, b0f)                                                      \
        MFMAQ(1, a0, b1f)                                                      \
        PH_END(6);                                                             \
        /* ---- phase B: quadrants (1,0), (1,1) — B frags persist ---- */      \
        LDA_HALF(a1, b, 1)                                                     \
        STAGE_A((b) ^ 1, 1, (kt) + 1);                                         \
        MFMAQ(2, a1, b0f)                                                      \
        MFMAQ(3, a1, b1f)                                                      \
        PH_END(2);                                                             \
    }

    STAGE_B(0, 0, 0); STAGE_B(0, 1, 0); STAGE_A(0, 0, 0);
    STAGE_A(0, 1, 0);
    PH_END(2);

    for (int kt = 0; kt < nk; kt += 2) {
        FRAME(0, kt)
        FRAME(1, kt + 1)
    }
#undef STAGE_A
#undef STAGE_B
#undef LDA_HALF
#undef LDB_HALF
#undef MFMAQ
#undef PH_END
#undef FRAME

    // epilogue: D layout col=lane&15, row=(lane>>4)*4+reg (m89-verified)
    float psum[2][2][4];
    if (EXPRS) {
#pragma unroll
        for (int ah = 0; ah < 2; ++ah)
#pragma unroll
            for (int mi2 = 0; mi2 < 2; ++mi2)
#pragma unroll
                for (int j = 0; j < 4; ++j) psum[ah][mi2][j] = 0.f;
    }
#pragma unroll
    for (int ah = 0; ah < 2; ++ah) {
#pragma unroll
        for (int bh = 0; bh < 2; ++bh) {
#pragma unroll
            for (int mi2 = 0; mi2 < 2; ++mi2) {
                float addm[4], mul[4];
#pragma unroll
                for (int j = 0; j < 4; ++j) {
                    const int rrow = m0 + ah * 128 + wrs * 32 + mi2 * 16 + lkg * 4 + j;
                    addm[j] = BIAS_M ? biasM[rrow] : 0.f;
                    if (DIVROW4) {
                        const float* r4 = rs + (long long)bz * 4096 + rrow;
                        mul[j] = 1.f / (r4[0] + r4[1024] + r4[2048] + r4[3072]);
                    } else mul[j] = 1.f;
                }
#pragma unroll
                for (int ni = 0; ni < 4; ++ni) {
                    const int col = n0 + bh * 128 + wcs * 64 + ni * 16 + lr16;
                    float bn = BIAS_N ? biasN[col] : 0.f;
#pragma unroll
                    for (int j = 0; j < 4; ++j) {
                        const int rrow = m0 + ah * 128 + wrs * 32 + mi2 * 16 + lkg * 4 + j;
                        float v2 = acc[ah * 2 + bh][mi2][ni][j] + addm[j] + bn;
                        v2 *= scale;
                        if (EXPRS) { v2 = __expf(v2 - 8.f); psum[ah][mi2][j] += v2; }
                        if (DIVROW4) v2 *= mul[j];
                        const long long idx = (long long)rrow * ldc + col;
                        if (RESID) {
                            float* Cf = (float*)Cv + (long long)bz * sC;
                            Cf[idx] = v2 + resid[(long long)bz * sC + idx];
                        } else {
                            short* Cs = (short*)Cv + (long long)bz * sC;
                            Cs[idx] = f2bf(v2);
                        }
                    }
                }
            }
        }
    }
    if (EXPRS) {
#pragma unroll
        for (int ah = 0; ah < 2; ++ah)
#pragma unroll
            for (int mi2 = 0; mi2 < 2; ++mi2)
#pragma unroll
                for (int j = 0; j < 4; ++j) {
                    float v = psum[ah][mi2][j];
                    v += __shfl_xor(v, 1); v += __shfl_xor(v, 2);
                    v += __shfl_xor(v, 4); v += __shfl_xor(v, 8);
                    psum[ah][mi2][j] = v;
                }
        float* scr = (float*)&lsA[1][0][0];
        __syncthreads();
        if (lr16 == 0) {
#pragma unroll
            for (int ah = 0; ah < 2; ++ah)
#pragma unroll
                for (int mi2 = 0; mi2 < 2; ++mi2)
#pragma unroll
                    for (int j = 0; j < 4; ++j)
                        scr[wcs * 256 + ah * 128 + wrs * 32 + mi2 * 16 + lkg * 4 + j]
                            = psum[ah][mi2][j];
        }
        __syncthreads();
        if (t < 256)
            rs[(long long)bz * 4096 + (n0 >> 8) * 1024 + m0 + t]
                = scr[t] + scr[256 + t];
    }
}

// ---------------------------------------------------------------------------
extern "C" void kernel_launch(void* const* d_in, const int* in_sizes, int n_in,
                              void* d_out, int out_size, void* d_ws, size_t ws_size,
                              hipStream_t stream)
{
    (void)in_sizes; (void)n_in; (void)out_size; (void)ws_size;
    const float* x     = (const float*)d_in[0];
    const float* gamma = (const float*)d_in[1];
    const float* beta  = (const float*)d_in[2];
    const float* Wq = (const float*)d_in[3];
    const float* bq = (const float*)d_in[4];
    const float* Wk = (const float*)d_in[5];
    const float* bk = (const float*)d_in[6];
    const float* Wv = (const float*)d_in[7];
    const float* bv = (const float*)d_in[8];
    const float* Wp = (const float*)d_in[9];
    const float* bp = (const float*)d_in[10];
    float* out = (float*)d_out;

    // Workspace (time-overlapped), high-water 162.51 MB — as R15:
    //   [0,32M):    hnT (b,c,t) bf16          (gn -> Phn)
    //   [32,96M):   qkb (b,s,1024) bf16       (qk -> expS); Phn reuses [32,64M)
    //   [96,128M):  hn blocked bf16           (gn -> qk, dead before expS)
    //   [96,160M):  expS (b,s,t) bf16         (expS -> Phn; overlays dead hn)
    //   [160,162M): wT slots {WqT*qs, WkT, WpT, Wv-cast}
    //   [162M..):   Avp (512K) | bqk (4K) | b2 (2K)
    //   rs4 (512K f32) lives in d_out: written by expS, read by Phn, then
    //   fully overwritten by the final out-GEMM (dead by then).
    char* ws = (char*)d_ws;
    short*  hnT  = (short*)ws;
    short*  qkb  = (short*)(ws + (32LL << 20));
    short*  hn   = (short*)(ws + (96LL << 20));
    short*  expS = (short*)(ws + (96LL << 20));   // overlays hn (dead)
    short*  wT   = (short*)(ws + (160LL << 20));
    short*  Avp  = (short*)(ws + (162LL << 20));
    float*  bqk  = (float*)(ws + (162LL << 20) + (512 << 10));
    float*  b2   = bqk + 1024;
    short*  Phn  = qkb;                            // reuses [32,64M)
    float*  rs4  = (float*)d_out;                  // scratch until out-GEMM

    const short* WqkT = wT;                        // slots 0-1 (1024 x 512)
    const short* WpT  = wT + 2 * 262144;
    const short* WvC  = wT + 3 * 262144;

    const float qscale = 0.044194173824159216f;    // 512^-0.5

    // --- precomputes (weights + biases in one launch, then Avp) ---
    prep_w<<<dim3(16, 16, 5), 256, 0, stream>>>(
        Wq, Wk, Wp, Wv, bq, bk, bp, bv, wT, bqk, b2, qscale);
    // Avp (d'',c) = sum_d WpT[d''][d] * Wv[c][d]  (= (Wv Wp)^T)
    small_nt<<<16, 256, 0, stream>>>(WpT, WvC, Avp, 1.f, 512, 512, 512, 512, 4);

    // --- main pipeline ---
    gn_fused<<<dim3(1024), 256, 0, stream>>>(x, gamma, beta, hn, hnT);

    // qk = hn @ [Wq*qs | Wk] + bqk : M=1024(s), N=1024, K=512 (hn blocked A)
    nt_gemm<0, 1, 0, 0, 0, 1, 0><<<512, 512, 0, stream>>>(
        hn, WqkT, qkb, nullptr, bqk, nullptr, nullptr, 1.f,
        512, 0, 512, 1024, 0, 0, 1024LL * 1024, 4, 16);
    // expS (s,t) = exp(q @ k^T - 8), rs4 partials : M=N=1024, K=512
    nt_gemm<0, 0, 0, 1, 0, 0, 0><<<512, 512, 0, stream>>>(
        qkb, qkb + 512, expS, nullptr, nullptr, nullptr, rs4, 1.f,
        512, 1024, 1024, 1024, 1024LL * 1024, 1024LL * 1024, 1024LL * 1024, 4, 16);
    // Phn (s,c) = (expS @ hnT^T) / rowsum : M=1024, N=512, K=1024
    nt_gemm<0, 0, 0, 0, 1, 0, 0><<<256, 512, 0, stream>>>(
        expS, hnT, Phn, nullptr, nullptr, nullptr, rs4, 1.f,
        1024, 1024, 1024, 512, 1024LL * 1024, 512LL * 1024, 512LL * 1024, 4, 8);
    // out (d'',s) = Avp @ Phn^T + b2 + x : M=512, N=1024, K=512, fp32
    nt_gemm<1, 0, 1, 0, 0, 0, 0><<<256, 512, 0, stream>>>(
        Avp, Phn, out, b2, nullptr, x, nullptr, 1.f,
        512, 512, 512, 1024, 0, 512LL * 1024, 512LL * 1024, 2, 8);
}